// Round 1
// baseline (259.437 us; speedup 1.0000x reference)
//
#include <hip/hip_runtime.h>
#include <hip/hip_bf16.h>

#define N_TOK 8192
#define DIN   1024
#define DOUT  1024
#define NE    8
#define BM    128
#define BN    128
#define BK    32
#define KTOT  (NE * DIN)          // 8192
#define NSTEP (KTOT / BK)         // 256

typedef __attribute__((ext_vector_type(4))) float f32x4;
typedef __attribute__((ext_vector_type(8))) short short8;
typedef unsigned int u32;

__device__ __forceinline__ ushort f2bf(float f) {
    u32 u = __float_as_uint(f);
    u32 r = (u + 0x7fffu + ((u >> 16) & 1u)) >> 16;   // round-to-nearest-even
    return (ushort)r;
}

__device__ __forceinline__ void gload_lds16(const void* gp, void* lp) {
    __builtin_amdgcn_global_load_lds(
        (const __attribute__((address_space(1))) u32*)gp,
        (__attribute__((address_space(3))) u32*)lp, 16, 0, 0);
}

// ---------------- gating: softmax(x @ Wg + bg) -> g [N_TOK][NE] (f32) -----------
__global__ void gate_kernel(const float* __restrict__ x, const float* __restrict__ Wg,
                            const float* __restrict__ bg, float* __restrict__ g) {
    int w = threadIdx.x >> 6, lane = threadIdx.x & 63;
    int n = blockIdx.x * 4 + w;
    const float* xr = x + (size_t)n * DIN;
    float p[NE];
#pragma unroll
    for (int e = 0; e < NE; ++e) p[e] = 0.f;
    for (int i = lane; i < DIN; i += 64) {
        float xv = xr[i];
        const float* wr_ = Wg + i * NE;
#pragma unroll
        for (int e = 0; e < NE; ++e) p[e] = fmaf(xv, wr_[e], p[e]);
    }
#pragma unroll
    for (int off = 32; off > 0; off >>= 1) {
#pragma unroll
        for (int e = 0; e < NE; ++e) p[e] += __shfl_down(p[e], off);
    }
    if (lane == 0) {
        float l2[NE], m = -1e30f;
#pragma unroll
        for (int e = 0; e < NE; ++e) { l2[e] = p[e] + bg[e]; m = fmaxf(m, l2[e]); }
        float s = 0.f;
#pragma unroll
        for (int e = 0; e < NE; ++e) { l2[e] = expf(l2[e] - m); s += l2[e]; }
        float inv = 1.f / s;
#pragma unroll
        for (int e = 0; e < NE; ++e) g[n * NE + e] = l2[e] * inv;
    }
}

// ---------------- x (f32) -> xb (bf16), 4 elems/thread --------------------------
__global__ void cvt_x_kernel(const float* __restrict__ x, ushort* __restrict__ xb) {
    int idx = blockIdx.x * 256 + threadIdx.x;
    float4 v = ((const float4*)x)[idx];
    ushort4 o = make_ushort4(f2bf(v.x), f2bf(v.y), f2bf(v.z), f2bf(v.w));
    ((ushort4*)xb)[idx] = o;
}

// ---------------- We [8192][1024] f32 -> BT [1024][8192] bf16 (transposed) ------
__global__ void transpose_w_kernel(const float* __restrict__ We, ushort* __restrict__ BT) {
    __shared__ float tile[64][65];
    int kb = blockIdx.x * 64, ob = blockIdx.y * 64;
    int t = threadIdx.x;
#pragma unroll
    for (int ph = 0; ph < 16; ++ph) {
        int idx = ph * 256 + t;
        int r = idx >> 6, c = idx & 63;
        tile[r][c] = We[(size_t)(kb + r) * DOUT + ob + c];
    }
    __syncthreads();
#pragma unroll
    for (int ph = 0; ph < 16; ++ph) {
        int idx = ph * 256 + t;
        int r = idx >> 6, c = idx & 63;
        BT[(size_t)(ob + r) * KTOT + kb + c] = f2bf(tile[c][r]);
    }
}

// ---------------- fused MoE GEMM: out = sum_e g_e * (x @ We_e) + sum_e g_e*be_e --
__global__ __launch_bounds__(256, 2) void moe_gemm(
    const ushort* __restrict__ xb,   // [8192][1024] bf16
    const ushort* __restrict__ BT,   // [1024][8192] bf16 (o-major, k-minor)
    const float*  __restrict__ g,    // [8192][8]
    const float*  __restrict__ be,   // [8][1024]
    float*        __restrict__ out)  // [8192][1024]
{
    __shared__ __align__(16) ushort Alds[2][BM][BK];
    __shared__ __align__(16) ushort Blds[2][BN][BK];

    int bid = blockIdx.x;
    // bijective XCD swizzle: 512 blocks, 8 XCDs, 64 per XCD
    int swz = (bid & 7) * 64 + (bid >> 3);
    int colb = swz & 7;           // 8 col blocks (DOUT/BN)
    int rowb = swz >> 3;          // 64 row blocks
    int brow = rowb * BM, bcol = colb * BN;

    int t = threadIdx.x;
    int w = t >> 6, lane = t & 63;
    int wr = (w >> 1) * 64, wc = (w & 1) * 64;   // 2x2 wave grid, 64x64 per wave

    f32x4 accF[4][4], accP[4][4];
#pragma unroll
    for (int m = 0; m < 4; ++m)
#pragma unroll
        for (int n = 0; n < 4; ++n)
#pragma unroll
            for (int j = 0; j < 4; ++j) { accF[m][n][j] = 0.f; accP[m][n][j] = 0.f; }

    // per-lane staging geometry: chunk q = (rr*4+w)*64 + lane; 8 elems each
    // row = q>>2, col = (q&3)*8 ; lds byte base (wave-uniform) = (rr*4+w)*1024
    int srow[2], scol[2];
#pragma unroll
    for (int rr = 0; rr < 2; ++rr) {
        int q = (rr * 4 + w) * 64 + lane;
        srow[rr] = q >> 2;
        scol[rr] = (q & 3) * 8;
    }

    // stage kt = 0
#pragma unroll
    for (int rr = 0; rr < 2; ++rr) {
        gload_lds16(xb + (size_t)(brow + srow[rr]) * DIN + scol[rr],
                    (char*)&Alds[0][0][0] + (rr * 4 + w) * 1024);
        gload_lds16(BT + (size_t)(bcol + srow[rr]) * KTOT + scol[rr],
                    (char*)&Blds[0][0][0] + (rr * 4 + w) * 1024);
    }
    __syncthreads();

    int cur = 0;
    int ro = lane & 15, ko = (lane >> 4) * 8;

    for (int kt = 0; kt < NSTEP; ++kt) {
        if (kt < NSTEP - 1) {
            int k2 = (kt + 1) * BK;           // global k
            int ka = k2 & (DIN - 1);          // within-expert k for A
#pragma unroll
            for (int rr = 0; rr < 2; ++rr) {
                gload_lds16(xb + (size_t)(brow + srow[rr]) * DIN + ka + scol[rr],
                            (char*)&Alds[cur ^ 1][0][0] + (rr * 4 + w) * 1024);
                gload_lds16(BT + (size_t)(bcol + srow[rr]) * KTOT + k2 + scol[rr],
                            (char*)&Blds[cur ^ 1][0][0] + (rr * 4 + w) * 1024);
            }
        }

        short8 af[4], bfr[4];
#pragma unroll
        for (int m = 0; m < 4; ++m)
            af[m] = *(const short8*)&Alds[cur][wr + m * 16 + ro][ko];
#pragma unroll
        for (int n = 0; n < 4; ++n)
            bfr[n] = *(const short8*)&Blds[cur][wc + n * 16 + ro][ko];
#pragma unroll
        for (int m = 0; m < 4; ++m)
#pragma unroll
            for (int n = 0; n < 4; ++n)
                accP[m][n] = __builtin_amdgcn_mfma_f32_16x16x32_bf16(
                    af[m], bfr[n], accP[m][n], 0, 0, 0);

        if ((kt & 31) == 31) {                 // expert boundary: fold with gate
            int e = kt >> 5;
#pragma unroll
            for (int m = 0; m < 4; ++m)
#pragma unroll
                for (int j = 0; j < 4; ++j) {
                    int grow = brow + wr + m * 16 + (lane >> 4) * 4 + j;
                    float gv = g[grow * NE + e];
#pragma unroll
                    for (int n = 0; n < 4; ++n) {
                        accF[m][n][j] += gv * accP[m][n][j];
                        accP[m][n][j] = 0.f;
                    }
                }
        }
        __syncthreads();
        cur ^= 1;
    }

    // epilogue: add gate-weighted bias, store f32
#pragma unroll
    for (int m = 0; m < 4; ++m) {
#pragma unroll
        for (int j = 0; j < 4; ++j) {
            int grow = brow + wr + m * 16 + (lane >> 4) * 4 + j;
            const float* gr = g + grow * NE;
            float g8[NE];
#pragma unroll
            for (int e = 0; e < NE; ++e) g8[e] = gr[e];
#pragma unroll
            for (int n = 0; n < 4; ++n) {
                int col = bcol + wc + n * 16 + (lane & 15);
                float bias = 0.f;
#pragma unroll
                for (int e = 0; e < NE; ++e) bias = fmaf(g8[e], be[e * DOUT + col], bias);
                out[(size_t)grow * DOUT + col] = accF[m][n][j] + bias;
            }
        }
    }
}

extern "C" void kernel_launch(void* const* d_in, const int* in_sizes, int n_in,
                              void* d_out, int out_size, void* d_ws, size_t ws_size,
                              hipStream_t stream) {
    const float* x  = (const float*)d_in[0];
    const float* We = (const float*)d_in[1];
    const float* be = (const float*)d_in[2];
    const float* Wg = (const float*)d_in[3];
    const float* bg = (const float*)d_in[4];
    float* out = (float*)d_out;

    char* ws = (char*)d_ws;
    float*  gbuf = (float*)ws;                                       // 256 KB
    ushort* xb   = (ushort*)(ws + (size_t)256 * 1024);               // 16 MB
    ushort* BT   = (ushort*)(ws + (size_t)256 * 1024 + (size_t)N_TOK * DIN * 2); // 16 MB

    gate_kernel<<<N_TOK / 4, 256, 0, stream>>>(x, Wg, bg, gbuf);
    cvt_x_kernel<<<(N_TOK * DIN / 4) / 256, 256, 0, stream>>>(x, xb);
    transpose_w_kernel<<<dim3(KTOT / 64, DOUT / 64), 256, 0, stream>>>(We, BT);
    moe_gemm<<<(N_TOK / BM) * (DOUT / BN), 256, 0, stream>>>(xb, BT, gbuf, be, out);
}